// Round 1
// baseline (836.433 us; speedup 1.0000x reference)
//
#include <hip/hip_runtime.h>

#define BB 1024
#define TB 512
#define FB 64
#define NH1 32
#define NH2 16
#define ND1 16
#define ND2 8

__device__ __forceinline__ float tanh_fast(float v) {
    // tanh(x) = 1 - 2/(e^{2x}+1); exp inf/0 limits give exactly +-1.
    float e = __expf(2.0f * v);
    return fmaf(-2.0f, __builtin_amdgcn_rcpf(e + 1.0f), 1.0f);
}

__global__ __launch_bounds__(64) void rnn_fused_kernel(
    const float* __restrict__ x,
    const float* __restrict__ Wx1, const float* __restrict__ Wh1, const float* __restrict__ b1,
    const float* __restrict__ Wx2, const float* __restrict__ Wh2, const float* __restrict__ b2,
    const float* __restrict__ W3,  const float* __restrict__ b3,
    const float* __restrict__ W4,  const float* __restrict__ b4,
    const float* __restrict__ Wo,  const float* __restrict__ bo,
    float* __restrict__ out)
{
    // One wave (64 threads) per batch element. LDS is private to this wave;
    // per-wave DS ops are in-order, so no barriers needed inside the t-loop.
    __shared__ __align__(16) float xs[2][FB];   // x_t staging, double buffer
    __shared__ __align__(16) float h1s[NH1];    // h1_{t-1} broadcast buffer
    __shared__ __align__(16) float h2s[NH2];    // h2 state
    __shared__ __align__(16) float ys[ND1];     // head temp

    const int lane = threadIdx.x;   // 0..63
    const int h = lane & 31;        // layer-1 output unit
    const int p = lane >> 5;        // f/j half (0,1)
    const int g = lane & 15;        // layer-2 output unit
    const int q = lane >> 4;        // quarter (0..3)
    const int b = blockIdx.x;

    // ---- preload weights into registers (one-time, coalesced across lanes) ----
    float wx1[32], wh1[16], wx2[8], wh2[4];
#pragma unroll
    for (int i = 0; i < 32; ++i) wx1[i] = Wx1[(32 * p + i) * NH1 + h];
#pragma unroll
    for (int i = 0; i < 16; ++i) wh1[i] = Wh1[(16 * p + i) * NH1 + h];
#pragma unroll
    for (int i = 0; i < 8; ++i)  wx2[i] = Wx2[(8 * q + i) * NH2 + g];
#pragma unroll
    for (int i = 0; i < 4; ++i)  wh2[i] = Wh2[(4 * q + i) * NH2 + g];
    const float b1v = (p == 0) ? b1[h] : 0.0f;  // added once after half-combine
    const float b2v = (q == 0) ? b2[g] : 0.0f;  // added once after quarter-combine

    // ---- init state ----
    if (lane < NH1) h1s[lane] = 0.0f;
    if (lane < NH2) h2s[lane] = 0.0f;

    // ---- x prefetch queue: 4 timesteps deep ----
    const float* xb = x + (size_t)b * TB * FB + lane;
    float xq[4];
#pragma unroll
    for (int i = 0; i < 4; ++i) xq[i] = xb[i * FB];
    xs[0][lane] = xq[0];
    __syncthreads();  // once, before the loop (single wave: cheap)

#pragma unroll 4
    for (int t = 0; t < TB; ++t) {
        const int slot = t & 1;
        // prefetch x_{t+4} into the queue slot freed by x_t (clamped at end)
        int tn = t + 4; tn = (tn < TB) ? tn : (TB - 1);
        xq[t & 3] = xb[tn * FB];
        // stage x_{t+1} into the other LDS slot
        xs[slot ^ 1][lane] = xq[(t + 1) & 3];

        // read h1_{t-1}[16p .. 16p+16) — 2 unique addrs per read = free broadcast
        float hv[16];
#pragma unroll
        for (int k = 0; k < 4; ++k) {
            float4 v = *(const float4*)&h1s[16 * p + 4 * k];
            hv[4*k+0] = v.x; hv[4*k+1] = v.y; hv[4*k+2] = v.z; hv[4*k+3] = v.w;
        }

        // ---- layer 1: xp1 partial (f in [32p,32p+32)) + rec1 partial (j in [16p,16p+16)) ----
        float a0 = b1v, a1 = 0.0f, a2 = 0.0f, a3 = 0.0f;  // 4-way acc tree
#pragma unroll
        for (int k = 0; k < 8; ++k) {
            float4 v = *(const float4*)&xs[slot][32 * p + 4 * k];
            a0 = fmaf(v.x, wx1[4*k+0], a0);
            a1 = fmaf(v.y, wx1[4*k+1], a1);
            a2 = fmaf(v.z, wx1[4*k+2], a2);
            a3 = fmaf(v.w, wx1[4*k+3], a3);
        }
#pragma unroll
        for (int i = 0; i < 16; i += 4) {
            a0 = fmaf(hv[i+0], wh1[i+0], a0);
            a1 = fmaf(hv[i+1], wh1[i+1], a1);
            a2 = fmaf(hv[i+2], wh1[i+2], a2);
            a3 = fmaf(hv[i+3], wh1[i+3], a3);
        }
        float acc = (a0 + a1) + (a2 + a3);
        acc += __shfl_xor(acc, 32, 64);       // combine halves; both halves now hold it
        float h1new = tanh_fast(acc);         // h1_t (redundant in both halves — by design)

        // ---- layer 2, pipelined one step behind: compute h2_{t-1} from hv = h1_{t-1} ----
        if (t > 0) {
            float c0 = b2v, c1 = 0.0f;
#pragma unroll
            for (int i = 0; i < 8; i += 2) {
                c0 = fmaf(hv[(q & 1) * 8 + i],     wx2[i],     c0);
                c1 = fmaf(hv[(q & 1) * 8 + i + 1], wx2[i + 1], c1);
            }
            float4 hw = *(const float4*)&h2s[4 * q];   // h2_{t-2}[4q..4q+4)
            c0 = fmaf(hw.x, wh2[0], c0);
            c1 = fmaf(hw.y, wh2[1], c1);
            c0 = fmaf(hw.z, wh2[2], c0);
            c1 = fmaf(hw.w, wh2[3], c1);
            float cc = c0 + c1;
            cc += __shfl_xor(cc, 16, 64);
            cc += __shfl_xor(cc, 32, 64);
            float h2new = tanh_fast(cc);
            if (lane < NH2) h2s[lane] = h2new;   // h2_{t-1}
        }

        if (p == 0) h1s[h] = h1new;              // publish h1_t for next iteration
    }

    // ---- epilogue: layer 2 for t = T-1 ----
    {
        float hv[16];
#pragma unroll
        for (int k = 0; k < 4; ++k) {
            float4 v = *(const float4*)&h1s[16 * p + 4 * k];
            hv[4*k+0] = v.x; hv[4*k+1] = v.y; hv[4*k+2] = v.z; hv[4*k+3] = v.w;
        }
        float c0 = b2v, c1 = 0.0f;
#pragma unroll
        for (int i = 0; i < 8; i += 2) {
            c0 = fmaf(hv[(q & 1) * 8 + i],     wx2[i],     c0);
            c1 = fmaf(hv[(q & 1) * 8 + i + 1], wx2[i + 1], c1);
        }
        float4 hw = *(const float4*)&h2s[4 * q];
        c0 = fmaf(hw.x, wh2[0], c0);
        c1 = fmaf(hw.y, wh2[1], c1);
        c0 = fmaf(hw.z, wh2[2], c0);
        c1 = fmaf(hw.w, wh2[3], c1);
        float cc = c0 + c1;
        cc += __shfl_xor(cc, 16, 64);
        cc += __shfl_xor(cc, 32, 64);
        float h2fin = tanh_fast(cc);
        if (lane < NH2) h2s[lane] = h2fin;
    }

    // ---- dense head (runs once; simplicity over speed) ----
    float a3h = b3[g];
#pragma unroll
    for (int j = 0; j < 16; ++j) a3h = fmaf(h2s[j], W3[j * ND1 + g], a3h);
    float y1 = fmaxf(a3h, 0.0f);
    if (lane < ND1) ys[lane] = y1;

    const int e = lane & 7;
    float a4 = b4[e];
#pragma unroll
    for (int j = 0; j < 16; ++j) a4 = fmaf(ys[j], W4[j * ND2 + e], a4);

    float yo = a4 * Wo[e];
    yo += __shfl_xor(yo, 1, 64);
    yo += __shfl_xor(yo, 2, 64);
    yo += __shfl_xor(yo, 4, 64);
    if (lane == 0) out[b] = yo + bo[0];
}

extern "C" void kernel_launch(void* const* d_in, const int* in_sizes, int n_in,
                              void* d_out, int out_size, void* d_ws, size_t ws_size,
                              hipStream_t stream) {
    const float* x   = (const float*)d_in[0];
    const float* Wx1 = (const float*)d_in[1];
    const float* Wh1 = (const float*)d_in[2];
    const float* b1  = (const float*)d_in[3];
    const float* Wx2 = (const float*)d_in[4];
    const float* Wh2 = (const float*)d_in[5];
    const float* b2  = (const float*)d_in[6];
    const float* W3  = (const float*)d_in[7];
    const float* b3  = (const float*)d_in[8];
    const float* W4  = (const float*)d_in[9];
    const float* b4  = (const float*)d_in[10];
    const float* Wo  = (const float*)d_in[11];
    const float* bo  = (const float*)d_in[12];
    float* out = (float*)d_out;

    rnn_fused_kernel<<<dim3(BB), dim3(64), 0, stream>>>(
        x, Wx1, Wh1, b1, Wx2, Wh2, b2, W3, b3, W4, b4, Wo, bo, out);
}

// Round 4
// 553.088 us; speedup vs baseline: 1.5123x; 1.5123x over previous
//
#include <hip/hip_runtime.h>

#define BB 1024
#define TB 512
#define FB 64
#define NH1 32
#define NH2 16
#define ND1 16
#define ND2 8

// Wavefront-scope fence: runtime-free (same-wave DS ops execute in issue
// order), but a hard compiler barrier against LDS read/write motion across
// it. Guards the cross-lane state handoff (masked publish -> next read).
#define WAVE_FENCE() __builtin_amdgcn_fence(__ATOMIC_ACQ_REL, "wavefront")

__device__ __forceinline__ float tanh_fast(float v) {
    // tanh(x) = 1 - 2/(e^{2x}+1); exp inf/0 limits give exactly +-1.
    float e = __expf(2.0f * v);
    return fmaf(-2.0f, __builtin_amdgcn_rcpf(e + 1.0f), 1.0f);
}

// One wave per batch element: 1024 waves = 1 wave/SIMD device-wide.
// (64,1): min 1 wave/EU -> VGPR budget up to 512 -> the ~60 weight registers
// stay resident (the default bound capped at 64 VGPRs and spilled them to
// scratch every timestep -> 706 us in round 1). Zero occupancy cost at
// 1 wave/SIMD.
__global__ __launch_bounds__(64, 1) void rnn_fused_kernel(
    const float* __restrict__ x,
    const float* __restrict__ Wx1, const float* __restrict__ Wh1, const float* __restrict__ b1,
    const float* __restrict__ Wx2, const float* __restrict__ Wh2, const float* __restrict__ b2,
    const float* __restrict__ W3,  const float* __restrict__ b3,
    const float* __restrict__ W4,  const float* __restrict__ b4,
    const float* __restrict__ Wo,  const float* __restrict__ bo,
    float* __restrict__ out)
{
    __shared__ __align__(16) float xs[2][FB];   // x_t staging, double buffer
    __shared__ __align__(16) float h1s[NH1];    // h1_{t-1} broadcast buffer
    __shared__ __align__(16) float h2s[NH2];    // h2 state
    __shared__ __align__(16) float ys[ND1];     // head temp

    const int lane = threadIdx.x;   // 0..63
    const int h = lane & 31;        // layer-1 output unit
    const int p = lane >> 5;        // half (0,1): f/j split for layer 1
    const int g = lane & 15;        // layer-2 output unit
    const int q = lane >> 4;        // quarter (0..3): input split for layer 2
    const int b = blockIdx.x;

    // ---- preload weights into registers (one-time, coalesced across lanes) ----
    float wx1[32], wh1[16], wx2[8], wh2[4];
#pragma unroll
    for (int i = 0; i < 32; ++i) wx1[i] = Wx1[(32 * p + i) * NH1 + h];
#pragma unroll
    for (int i = 0; i < 16; ++i) wh1[i] = Wh1[(16 * p + i) * NH1 + h];
#pragma unroll
    for (int i = 0; i < 8; ++i)  wx2[i] = Wx2[(8 * q + i) * NH2 + g];
#pragma unroll
    for (int i = 0; i < 4; ++i)  wh2[i] = Wh2[(4 * q + i) * NH2 + g];
    const float b1v = (p == 0) ? b1[h] : 0.0f;  // added once after half-combine
    const float b2v = (q == 0) ? b2[g] : 0.0f;  // added once after quarter-combine

    // ---- init state ----
    if (lane < NH1) h1s[lane] = 0.0f;
    if (lane < NH2) h2s[lane] = 0.0f;

    // ---- x prefetch queue: 4 timesteps deep (lane = feature index) ----
    const float* xb = x + (size_t)b * TB * FB + lane;
    float xq[4];
#pragma unroll
    for (int i = 0; i < 4; ++i) xq[i] = xb[i * FB];
    xs[0][lane] = xq[0];
    __syncthreads();  // once, before the loop

#pragma unroll 2
    for (int t = 0; t < TB; ++t) {
        // Iteration boundary: no LDS op may move across this point.
        WAVE_FENCE();

        const int slot = t & 1;
        // prefetch x_{t+4} into the queue slot freed by x_t (clamped at end)
        int tn = t + 4; tn = (tn < TB) ? tn : (TB - 1);
        xq[t & 3] = xb[tn * FB];
        // stage x_{t+1} into the other LDS slot
        xs[slot ^ 1][lane] = xq[(t + 1) & 3];

        // read h1_{t-1}[16p .. 16p+16) — 2 unique addrs per read = free broadcast
        float4 hva = *(const float4*)&h1s[16 * p + 0];
        float4 hvb = *(const float4*)&h1s[16 * p + 4];
        float4 hvc = *(const float4*)&h1s[16 * p + 8];
        float4 hvd = *(const float4*)&h1s[16 * p + 12];

        // ---- layer 1: xp1 partial (f in [32p,32p+32)) + rec1 partial ----
        float a0 = b1v, a1 = 0.0f, a2 = 0.0f, a3 = 0.0f;  // 4-way acc tree
        const float4* xv = (const float4*)&xs[slot][32 * p];
#pragma unroll
        for (int k = 0; k < 8; ++k) {
            float4 v = xv[k];
            a0 = fmaf(v.x, wx1[4*k+0], a0);
            a1 = fmaf(v.y, wx1[4*k+1], a1);
            a2 = fmaf(v.z, wx1[4*k+2], a2);
            a3 = fmaf(v.w, wx1[4*k+3], a3);
        }
        a0 = fmaf(hva.x, wh1[0],  a0);  a1 = fmaf(hva.y, wh1[1],  a1);
        a2 = fmaf(hva.z, wh1[2],  a2);  a3 = fmaf(hva.w, wh1[3],  a3);
        a0 = fmaf(hvb.x, wh1[4],  a0);  a1 = fmaf(hvb.y, wh1[5],  a1);
        a2 = fmaf(hvb.z, wh1[6],  a2);  a3 = fmaf(hvb.w, wh1[7],  a3);
        a0 = fmaf(hvc.x, wh1[8],  a0);  a1 = fmaf(hvc.y, wh1[9],  a1);
        a2 = fmaf(hvc.z, wh1[10], a2);  a3 = fmaf(hvc.w, wh1[11], a3);
        a0 = fmaf(hvd.x, wh1[12], a0);  a1 = fmaf(hvd.y, wh1[13], a1);
        a2 = fmaf(hvd.z, wh1[14], a2);  a3 = fmaf(hvd.w, wh1[15], a3);
        float acc = (a0 + a1) + (a2 + a3);
        acc += __shfl_xor(acc, 32, 64);       // combine halves
        float h1new = tanh_fast(acc);         // h1_t (both halves hold it)

        // ---- layer 2, pipelined one step behind: h2_{t-1} from h1_{t-1} ----
        // (h1s still holds h1_{t-1}; publish of h1_t happens below)
        if (t > 0) {
            float4 u0 = *(const float4*)&h1s[8 * q + 0];   // h1_{t-1}[8q..8q+4)
            float4 u1 = *(const float4*)&h1s[8 * q + 4];   // h1_{t-1}[8q+4..8q+8)
            float4 hw = *(const float4*)&h2s[4 * q];       // h2_{t-2}[4q..4q+4)
            float c0 = b2v, c1 = 0.0f;
            c0 = fmaf(u0.x, wx2[0], c0);  c1 = fmaf(u0.y, wx2[1], c1);
            c0 = fmaf(u0.z, wx2[2], c0);  c1 = fmaf(u0.w, wx2[3], c1);
            c0 = fmaf(u1.x, wx2[4], c0);  c1 = fmaf(u1.y, wx2[5], c1);
            c0 = fmaf(u1.z, wx2[6], c0);  c1 = fmaf(u1.w, wx2[7], c1);
            c0 = fmaf(hw.x, wh2[0], c0);  c1 = fmaf(hw.y, wh2[1], c1);
            c0 = fmaf(hw.z, wh2[2], c0);  c1 = fmaf(hw.w, wh2[3], c1);
            float cc = c0 + c1;
            cc += __shfl_xor(cc, 16, 64);
            cc += __shfl_xor(cc, 32, 64);
            float h2new = tanh_fast(cc);
            if (lane < NH2) h2s[lane] = h2new;   // h2_{t-1}
        }

        // no read of h1s below this point in the iteration
        WAVE_FENCE();
        if (p == 0) h1s[h] = h1new;              // publish h1_t for next iter
    }

    WAVE_FENCE();

    // ---- epilogue: layer 2 for t = T-1 ----
    {
        float4 u0 = *(const float4*)&h1s[8 * q + 0];
        float4 u1 = *(const float4*)&h1s[8 * q + 4];
        float4 hw = *(const float4*)&h2s[4 * q];
        float c0 = b2v, c1 = 0.0f;
        c0 = fmaf(u0.x, wx2[0], c0);  c1 = fmaf(u0.y, wx2[1], c1);
        c0 = fmaf(u0.z, wx2[2], c0);  c1 = fmaf(u0.w, wx2[3], c1);
        c0 = fmaf(u1.x, wx2[4], c0);  c1 = fmaf(u1.y, wx2[5], c1);
        c0 = fmaf(u1.z, wx2[6], c0);  c1 = fmaf(u1.w, wx2[7], c1);
        c0 = fmaf(hw.x, wh2[0], c0);  c1 = fmaf(hw.y, wh2[1], c1);
        c0 = fmaf(hw.z, wh2[2], c0);  c1 = fmaf(hw.w, wh2[3], c1);
        float cc = c0 + c1;
        cc += __shfl_xor(cc, 16, 64);
        cc += __shfl_xor(cc, 32, 64);
        float h2fin = tanh_fast(cc);
        WAVE_FENCE();
        if (lane < NH2) h2s[lane] = h2fin;
        WAVE_FENCE();
    }

    // ---- dense head (scalar round-1 form, known good) ----
    float a3h = b3[g];
#pragma unroll
    for (int j = 0; j < 16; ++j) a3h = fmaf(h2s[j], W3[j * ND1 + g], a3h);
    float y1 = fmaxf(a3h, 0.0f);
    WAVE_FENCE();
    if (lane < ND1) ys[lane] = y1;
    WAVE_FENCE();

    const int e = lane & 7;
    float a4 = b4[e];
#pragma unroll
    for (int j = 0; j < 16; ++j) a4 = fmaf(ys[j], W4[j * ND2 + e], a4);

    float yo = a4 * Wo[e];
    yo += __shfl_xor(yo, 1, 64);
    yo += __shfl_xor(yo, 2, 64);
    yo += __shfl_xor(yo, 4, 64);
    if (lane == 0) out[b] = yo + bo[0];
}

extern "C" void kernel_launch(void* const* d_in, const int* in_sizes, int n_in,
                              void* d_out, int out_size, void* d_ws, size_t ws_size,
                              hipStream_t stream) {
    const float* x   = (const float*)d_in[0];
    const float* Wx1 = (const float*)d_in[1];
    const float* Wh1 = (const float*)d_in[2];
    const float* b1  = (const float*)d_in[3];
    const float* Wx2 = (const float*)d_in[4];
    const float* Wh2 = (const float*)d_in[5];
    const float* b2  = (const float*)d_in[6];
    const float* W3  = (const float*)d_in[7];
    const float* b3  = (const float*)d_in[8];
    const float* W4  = (const float*)d_in[9];
    const float* b4  = (const float*)d_in[10];
    const float* Wo  = (const float*)d_in[11];
    const float* bo  = (const float*)d_in[12];
    float* out = (float*)d_out;

    rnn_fused_kernel<<<dim3(BB), dim3(64), 0, stream>>>(
        x, Wx1, Wh1, b1, Wx2, Wh2, b2, W3, b3, W4, b4, Wo, bo, out);
}

// Round 5
// 363.498 us; speedup vs baseline: 2.3011x; 1.5216x over previous
//
#include <hip/hip_runtime.h>

#define BB 1024
#define TB 512
#define FB 64
#define NH1 32
#define NH2 16
#define ND1 16
#define ND2 8

// Wavefront-scope fence: runtime-free, but a hard compiler barrier against
// LDS motion across the masked-publish -> cross-lane-read handoff.
#define WAVE_FENCE() __builtin_amdgcn_fence(__ATOMIC_ACQ_REL, "wavefront")

__device__ __forceinline__ float tanh_fast(float v) {
    // tanh(x) = 1 - 2/(e^{2x}+1); exp inf/0 limits give exactly +-1.
    float e = __expf(2.0f * v);
    return fmaf(-2.0f, __builtin_amdgcn_rcpf(e + 1.0f), 1.0f);
}

// One wave per batch element: 1024 waves = 1 wave/SIMD device-wide.
// Explicit backend attributes (NOT launch_bounds, which left the VGPR cap at
// 64 in round 4): exactly 1 wave/EU -> register budget up to 512 VGPRs, so
// the ~60 weight values stay resident instead of spilling every timestep.
__global__ __attribute__((amdgpu_flat_work_group_size(64, 64)))
           __attribute__((amdgpu_waves_per_eu(1, 1)))
void rnn_fused_kernel(
    const float* __restrict__ x,
    const float* __restrict__ Wx1, const float* __restrict__ Wh1, const float* __restrict__ b1,
    const float* __restrict__ Wx2, const float* __restrict__ Wh2, const float* __restrict__ b2,
    const float* __restrict__ W3,  const float* __restrict__ b3,
    const float* __restrict__ W4,  const float* __restrict__ b4,
    const float* __restrict__ Wo,  const float* __restrict__ bo,
    float* __restrict__ out)
{
    __shared__ __align__(16) float xs[2][FB];   // x_t staging, double buffer
    __shared__ __align__(16) float h1s[NH1];    // h1_{t-1} broadcast buffer
    __shared__ __align__(16) float h2s[NH2];    // h2 state
    __shared__ __align__(16) float ys[ND1];     // head temp

    const int lane = threadIdx.x;   // 0..63
    const int h = lane & 31;        // layer-1 output unit
    const int p = lane >> 5;        // half (0,1): f/j split for layer 1
    const int g = lane & 15;        // layer-2 output unit
    const int q = lane >> 4;        // quarter (0..3): input split for layer 2
    const int b = blockIdx.x;

    // ---- weights as NAMED float4 registers (no arrays -> no scratch risk) ----
    auto w1 = [&](int i) { return Wx1[(32 * p + i) * NH1 + h]; };
    auto r1 = [&](int i) { return Wh1[(16 * p + i) * NH1 + h]; };
    auto w2 = [&](int i) { return Wx2[(8 * q + i) * NH2 + g]; };
    auto r2 = [&](int i) { return Wh2[(4 * q + i) * NH2 + g]; };
    const float4 wxa = make_float4(w1(0),  w1(1),  w1(2),  w1(3));
    const float4 wxb = make_float4(w1(4),  w1(5),  w1(6),  w1(7));
    const float4 wxc = make_float4(w1(8),  w1(9),  w1(10), w1(11));
    const float4 wxd = make_float4(w1(12), w1(13), w1(14), w1(15));
    const float4 wxe = make_float4(w1(16), w1(17), w1(18), w1(19));
    const float4 wxf = make_float4(w1(20), w1(21), w1(22), w1(23));
    const float4 wxg = make_float4(w1(24), w1(25), w1(26), w1(27));
    const float4 wxh = make_float4(w1(28), w1(29), w1(30), w1(31));
    const float4 wha = make_float4(r1(0),  r1(1),  r1(2),  r1(3));
    const float4 whb = make_float4(r1(4),  r1(5),  r1(6),  r1(7));
    const float4 whc = make_float4(r1(8),  r1(9),  r1(10), r1(11));
    const float4 whd = make_float4(r1(12), r1(13), r1(14), r1(15));
    const float4 x2a = make_float4(w2(0), w2(1), w2(2), w2(3));
    const float4 x2b = make_float4(w2(4), w2(5), w2(6), w2(7));
    const float4 h2w = make_float4(r2(0), r2(1), r2(2), r2(3));
    const float b1v = (p == 0) ? b1[h] : 0.0f;  // added once after half-combine
    const float b2v = (q == 0) ? b2[g] : 0.0f;  // added once after quarter-combine

    // ---- init state ----
    if (lane < NH1) h1s[lane] = 0.0f;
    if (lane < NH2) h2s[lane] = 0.0f;

    // ---- x prefetch queue: 4 named scalars (manual rotation, no indexing) ----
    const float* xb = x + (size_t)b * TB * FB + lane;
    float xq0 = xb[0 * FB];
    float xq1 = xb[1 * FB];
    float xq2 = xb[2 * FB];
    float xq3 = xb[3 * FB];
    xs[0][lane] = xq0;
    __syncthreads();  // once, before the loop

// One timestep. SLOT = t&1 (compile-time). QSTAGE = queue scalar holding
// x_{t+1} (written to LDS now). QREFILL = queue scalar freed this step
// (receives x_{t+4}). The vmcnt wait for the refill load lands 4 steps
// later, at its QSTAGE ds_write -> ~4 steps of latency cover.
#define STEP(T, SLOT, QSTAGE, QREFILL)                                         \
    {                                                                          \
        WAVE_FENCE(); /* iteration boundary: no LDS motion across */           \
        const int t_ = (T);                                                    \
        int tn_ = t_ + 4; tn_ = (tn_ < TB) ? tn_ : (TB - 1);                   \
        const float xnew_ = xb[tn_ * FB];                                      \
        xs[(SLOT) ^ 1][lane] = QSTAGE;                                         \
        float4 hva = *(const float4*)&h1s[16 * p + 0];                         \
        float4 hvb = *(const float4*)&h1s[16 * p + 4];                         \
        float4 hvc = *(const float4*)&h1s[16 * p + 8];                         \
        float4 hvd = *(const float4*)&h1s[16 * p + 12];                        \
        const float4* xv = (const float4*)&xs[SLOT][32 * p];                   \
        float a0 = b1v, a1 = 0.0f, a2 = 0.0f, a3 = 0.0f;                       \
        float4 v_;                                                             \
        v_ = xv[0]; a0 = fmaf(v_.x, wxa.x, a0); a1 = fmaf(v_.y, wxa.y, a1);    \
                    a2 = fmaf(v_.z, wxa.z, a2); a3 = fmaf(v_.w, wxa.w, a3);    \
        v_ = xv[1]; a0 = fmaf(v_.x, wxb.x, a0); a1 = fmaf(v_.y, wxb.y, a1);    \
                    a2 = fmaf(v_.z, wxb.z, a2); a3 = fmaf(v_.w, wxb.w, a3);    \
        v_ = xv[2]; a0 = fmaf(v_.x, wxc.x, a0); a1 = fmaf(v_.y, wxc.y, a1);    \
                    a2 = fmaf(v_.z, wxc.z, a2); a3 = fmaf(v_.w, wxc.w, a3);    \
        v_ = xv[3]; a0 = fmaf(v_.x, wxd.x, a0); a1 = fmaf(v_.y, wxd.y, a1);    \
                    a2 = fmaf(v_.z, wxd.z, a2); a3 = fmaf(v_.w, wxd.w, a3);    \
        v_ = xv[4]; a0 = fmaf(v_.x, wxe.x, a0); a1 = fmaf(v_.y, wxe.y, a1);    \
                    a2 = fmaf(v_.z, wxe.z, a2); a3 = fmaf(v_.w, wxe.w, a3);    \
        v_ = xv[5]; a0 = fmaf(v_.x, wxf.x, a0); a1 = fmaf(v_.y, wxf.y, a1);    \
                    a2 = fmaf(v_.z, wxf.z, a2); a3 = fmaf(v_.w, wxf.w, a3);    \
        v_ = xv[6]; a0 = fmaf(v_.x, wxg.x, a0); a1 = fmaf(v_.y, wxg.y, a1);    \
                    a2 = fmaf(v_.z, wxg.z, a2); a3 = fmaf(v_.w, wxg.w, a3);    \
        v_ = xv[7]; a0 = fmaf(v_.x, wxh.x, a0); a1 = fmaf(v_.y, wxh.y, a1);    \
                    a2 = fmaf(v_.z, wxh.z, a2); a3 = fmaf(v_.w, wxh.w, a3);    \
        a0 = fmaf(hva.x, wha.x, a0); a1 = fmaf(hva.y, wha.y, a1);              \
        a2 = fmaf(hva.z, wha.z, a2); a3 = fmaf(hva.w, wha.w, a3);              \
        a0 = fmaf(hvb.x, whb.x, a0); a1 = fmaf(hvb.y, whb.y, a1);              \
        a2 = fmaf(hvb.z, whb.z, a2); a3 = fmaf(hvb.w, whb.w, a3);              \
        a0 = fmaf(hvc.x, whc.x, a0); a1 = fmaf(hvc.y, whc.y, a1);              \
        a2 = fmaf(hvc.z, whc.z, a2); a3 = fmaf(hvc.w, whc.w, a3);              \
        a0 = fmaf(hvd.x, whd.x, a0); a1 = fmaf(hvd.y, whd.y, a1);              \
        a2 = fmaf(hvd.z, whd.z, a2); a3 = fmaf(hvd.w, whd.w, a3);              \
        float acc = (a0 + a1) + (a2 + a3);                                     \
        acc += __shfl_xor(acc, 32, 64);                                        \
        float h1new = tanh_fast(acc);                                          \
        if (t_ > 0) {  /* layer 2, one step behind: h2_{t-1} from h1_{t-1} */  \
            float4 u0 = *(const float4*)&h1s[8 * q + 0];                       \
            float4 u1 = *(const float4*)&h1s[8 * q + 4];                       \
            float4 hw = *(const float4*)&h2s[4 * q];                           \
            float c0 = b2v, c1 = 0.0f;                                         \
            c0 = fmaf(u0.x, x2a.x, c0); c1 = fmaf(u0.y, x2a.y, c1);            \
            c0 = fmaf(u0.z, x2a.z, c0); c1 = fmaf(u0.w, x2a.w, c1);            \
            c0 = fmaf(u1.x, x2b.x, c0); c1 = fmaf(u1.y, x2b.y, c1);            \
            c0 = fmaf(u1.z, x2b.z, c0); c1 = fmaf(u1.w, x2b.w, c1);            \
            c0 = fmaf(hw.x, h2w.x, c0); c1 = fmaf(hw.y, h2w.y, c1);            \
            c0 = fmaf(hw.z, h2w.z, c0); c1 = fmaf(hw.w, h2w.w, c1);            \
            float cc = c0 + c1;                                                \
            cc += __shfl_xor(cc, 16, 64);                                      \
            cc += __shfl_xor(cc, 32, 64);                                      \
            float h2new = tanh_fast(cc);                                       \
            if (lane < NH2) h2s[lane] = h2new;                                 \
        }                                                                      \
        WAVE_FENCE(); /* no h1s read below this point in the iteration */      \
        if (p == 0) h1s[h] = h1new;                                            \
        QREFILL = xnew_;                                                       \
    }

    for (int tb = 0; tb < TB; tb += 4) {
        STEP(tb + 0, 0, xq1, xq0);
        STEP(tb + 1, 1, xq2, xq1);
        STEP(tb + 2, 0, xq3, xq2);
        STEP(tb + 3, 1, xq0, xq3);
    }
#undef STEP

    WAVE_FENCE();

    // ---- epilogue: layer 2 for t = T-1 ----
    {
        float4 u0 = *(const float4*)&h1s[8 * q + 0];
        float4 u1 = *(const float4*)&h1s[8 * q + 4];
        float4 hw = *(const float4*)&h2s[4 * q];
        float c0 = b2v, c1 = 0.0f;
        c0 = fmaf(u0.x, x2a.x, c0); c1 = fmaf(u0.y, x2a.y, c1);
        c0 = fmaf(u0.z, x2a.z, c0); c1 = fmaf(u0.w, x2a.w, c1);
        c0 = fmaf(u1.x, x2b.x, c0); c1 = fmaf(u1.y, x2b.y, c1);
        c0 = fmaf(u1.z, x2b.z, c0); c1 = fmaf(u1.w, x2b.w, c1);
        c0 = fmaf(hw.x, h2w.x, c0); c1 = fmaf(hw.y, h2w.y, c1);
        c0 = fmaf(hw.z, h2w.z, c0); c1 = fmaf(hw.w, h2w.w, c1);
        float cc = c0 + c1;
        cc += __shfl_xor(cc, 16, 64);
        cc += __shfl_xor(cc, 32, 64);
        float h2fin = tanh_fast(cc);
        WAVE_FENCE();
        if (lane < NH2) h2s[lane] = h2fin;
        WAVE_FENCE();
    }

    // ---- dense head (scalar form, known good) ----
    float a3h = b3[g];
#pragma unroll
    for (int j = 0; j < 16; ++j) a3h = fmaf(h2s[j], W3[j * ND1 + g], a3h);
    float y1 = fmaxf(a3h, 0.0f);
    WAVE_FENCE();
    if (lane < ND1) ys[lane] = y1;
    WAVE_FENCE();

    const int e = lane & 7;
    float a4 = b4[e];
#pragma unroll
    for (int j = 0; j < 16; ++j) a4 = fmaf(ys[j], W4[j * ND2 + e], a4);

    float yo = a4 * Wo[e];
    yo += __shfl_xor(yo, 1, 64);
    yo += __shfl_xor(yo, 2, 64);
    yo += __shfl_xor(yo, 4, 64);
    if (lane == 0) out[b] = yo + bo[0];
}

extern "C" void kernel_launch(void* const* d_in, const int* in_sizes, int n_in,
                              void* d_out, int out_size, void* d_ws, size_t ws_size,
                              hipStream_t stream) {
    const float* x   = (const float*)d_in[0];
    const float* Wx1 = (const float*)d_in[1];
    const float* Wh1 = (const float*)d_in[2];
    const float* b1  = (const float*)d_in[3];
    const float* Wx2 = (const float*)d_in[4];
    const float* Wh2 = (const float*)d_in[5];
    const float* b2  = (const float*)d_in[6];
    const float* W3  = (const float*)d_in[7];
    const float* b3  = (const float*)d_in[8];
    const float* W4  = (const float*)d_in[9];
    const float* b4  = (const float*)d_in[10];
    const float* Wo  = (const float*)d_in[11];
    const float* bo  = (const float*)d_in[12];
    float* out = (float*)d_out;

    rnn_fused_kernel<<<dim3(BB), dim3(64), 0, stream>>>(
        x, Wx1, Wh1, b1, Wx2, Wh2, b2, W3, b3, W4, b4, Wo, bo, out);
}